// Round 1
// baseline (77.709 us; speedup 1.0000x reference)
//
#include <hip/hip_runtime.h>
#include <hip/hip_bf16.h>

#define NN 4096
#define IN_DIM 512
#define OUT_D 64
#define LOG2E 1.44269504088896340736f

typedef __attribute__((ext_vector_type(8))) short short8v;
typedef __attribute__((ext_vector_type(4))) float f32x4;

__device__ __forceinline__ short to_bf16_rne(float x) {
  unsigned u = __builtin_bit_cast(unsigned, x);
  u = (u + 0x7FFFu + ((u >> 16) & 1u)) >> 16;
  return (short)u;
}

// ---------------- Kernel 1: h = X @ W ; write hbT (bf16, transposed [64][4096]),
// s1 = (h@a1)*log2e, s2 = (h@a2)*log2e ----------------
__global__ __launch_bounds__(256) void k_h(
    const float* __restrict__ X, const float* __restrict__ W,
    const float* __restrict__ a,
    short* __restrict__ hbT, float* __restrict__ s1, float* __restrict__ s2)
{
  int tid = threadIdx.x;
  int dp = tid & 31;           // d-pair: d = 2*dp
  int rw = tid >> 5;           // 0..7 rows per block
  int row = blockIdx.x * 8 + rw;
  const float* xrow = X + (size_t)row * IN_DIM;
  int d = dp * 2;
  float acc0 = 0.f, acc1 = 0.f;
  #pragma unroll 4
  for (int k4 = 0; k4 < IN_DIM / 4; ++k4) {
    float4 xv = *(const float4*)(xrow + k4 * 4);
    float2 w0 = *(const float2*)(W + (k4 * 4 + 0) * OUT_D + d);
    float2 w1 = *(const float2*)(W + (k4 * 4 + 1) * OUT_D + d);
    float2 w2 = *(const float2*)(W + (k4 * 4 + 2) * OUT_D + d);
    float2 w3 = *(const float2*)(W + (k4 * 4 + 3) * OUT_D + d);
    acc0 = fmaf(xv.x, w0.x, acc0); acc1 = fmaf(xv.x, w0.y, acc1);
    acc0 = fmaf(xv.y, w1.x, acc0); acc1 = fmaf(xv.y, w1.y, acc1);
    acc0 = fmaf(xv.z, w2.x, acc0); acc1 = fmaf(xv.z, w2.y, acc1);
    acc0 = fmaf(xv.w, w3.x, acc0); acc1 = fmaf(xv.w, w3.y, acc1);
  }
  hbT[(size_t)d * NN + row]       = to_bf16_rne(acc0);
  hbT[(size_t)(d + 1) * NN + row] = to_bf16_rne(acc1);
  float p1 = a[d] * acc0 + a[d + 1] * acc1;
  float p2 = a[OUT_D + d] * acc0 + a[OUT_D + d + 1] * acc1;
  #pragma unroll
  for (int off = 16; off >= 1; off >>= 1) {
    p1 += __shfl_xor(p1, off);
    p2 += __shfl_xor(p2, off);
  }
  if (dp == 0) {
    s1[row] = p1 * LOG2E;   // pre-scaled by log2(e); leaky is positively homogeneous
    s2[row] = p2 * LOG2E;
  }
}

// ---------------- Kernel 2: global max of (scaled) s2 ----------------
__global__ __launch_bounds__(256) void k_s2max(const float* __restrict__ s2,
                                               float* __restrict__ s2max)
{
  __shared__ float red[256];
  float m = -3.0e38f;
  for (int i = threadIdx.x; i < NN; i += 256) m = fmaxf(m, s2[i]);
  red[threadIdx.x] = m;
  __syncthreads();
  for (int s = 128; s > 0; s >>= 1) {
    if ((int)threadIdx.x < s) red[threadIdx.x] = fmaxf(red[threadIdx.x], red[threadIdx.x + s]);
    __syncthreads();
  }
  if (threadIdx.x == 0) *s2max = red[0];
}

// ---------------- Kernel 3: fused masked-softmax-weight + P@H via MFMA ----------------
// Wave = one 16-row M-tile; block = 4 waves = 64 rows; grid = (64 rowblocks, NPART j-parts).
// P tile built directly in A-fragment layout; B from hbT (8 contiguous bf16 per lane).
__global__ __launch_bounds__(256) void k_attn(
    const int* __restrict__ adj, const short* __restrict__ hbT,
    const float* __restrict__ s1, const float* __restrict__ s2,
    const float* __restrict__ s2maxp,
    float* __restrict__ accp, float* __restrict__ lpart, int jchunk)
{
  int w  = threadIdx.x >> 6;
  int l  = threadIdx.x & 63;
  int lo = l & 15, g = l >> 4;
  int part  = blockIdx.y;
  int ibase = blockIdx.x * 64 + w * 16;
  int row   = ibase + lo;

  float s1v = s1[row];
  float x = s1v + *s2maxp;
  float M = fmaxf(x, 0.01f * x);   // row-constant upper bound on all scores (scaled)

  f32x4 c0 = {0.f,0.f,0.f,0.f}, c1 = {0.f,0.f,0.f,0.f};
  f32x4 c2 = {0.f,0.f,0.f,0.f}, c3 = {0.f,0.f,0.f,0.f};
  float lsum = 0.f;

  const int* adjrow = adj + (size_t)row * NN;
  int j0 = part * jchunk;
  int jj = j0 + g * 8;

  int4  pa0 = *(const int4*)(adjrow + jj);
  int4  pa1 = *(const int4*)(adjrow + jj + 4);
  float4 ps0 = *(const float4*)(s2 + jj);
  float4 ps1 = *(const float4*)(s2 + jj + 4);

  for (int js = 0; js < jchunk; js += 32) {
    int4 a0 = pa0, a1 = pa1;
    float4 t0 = ps0, t1 = ps1;
    int jn = jj + 32;
    if (js + 32 < jchunk) {            // 1-deep prefetch of next adj/s2 chunk
      pa0 = *(const int4*)(adjrow + jn);
      pa1 = *(const int4*)(adjrow + jn + 4);
      ps0 = *(const float4*)(s2 + jn);
      ps1 = *(const float4*)(s2 + jn + 4);
    }

    short8v b0 = *(const short8v*)(hbT + ((size_t)(lo)      << 12) + jj);
    short8v b1 = *(const short8v*)(hbT + ((size_t)(16 + lo) << 12) + jj);
    short8v b2 = *(const short8v*)(hbT + ((size_t)(32 + lo) << 12) + jj);
    short8v b3 = *(const short8v*)(hbT + ((size_t)(48 + lo) << 12) + jj);

    int av[8]; float sv[8];
    *(int4*)(av) = a0;  *(int4*)(av + 4) = a1;
    *(float4*)(sv) = t0; *(float4*)(sv + 4) = t1;

    short8v af;
    #pragma unroll
    for (int r = 0; r < 8; ++r) {
      float y = s1v + sv[r];
      float e = fmaxf(y, 0.01f * y);   // leaky-relu (scaled domain)
      float p = exp2f(e - M);
      p = (av[r] > 0) ? p : 0.f;
      lsum += p;
      af[r] = to_bf16_rne(p);
    }

    c0 = __builtin_amdgcn_mfma_f32_16x16x32_bf16(af, b0, c0, 0, 0, 0);
    c1 = __builtin_amdgcn_mfma_f32_16x16x32_bf16(af, b1, c1, 0, 0, 0);
    c2 = __builtin_amdgcn_mfma_f32_16x16x32_bf16(af, b2, c2, 0, 0, 0);
    c3 = __builtin_amdgcn_mfma_f32_16x16x32_bf16(af, b3, c3, 0, 0, 0);
    jj = jn;
  }

  // row-sum of weights: lanes {lo, lo+16, lo+32, lo+48} hold partials of row ibase+lo
  lsum += __shfl_xor(lsum, 16);
  lsum += __shfl_xor(lsum, 32);
  if (l < 16) lpart[(size_t)part * NN + ibase + l] = lsum;

  // C/D layout (m89-verified): col = lane&15, row = (lane>>4)*4 + reg
  float* ap = accp + ((size_t)part * NN + ibase) * OUT_D;
  #pragma unroll
  for (int q = 0; q < 4; ++q) {
    int ri = g * 4 + q;
    ap[ri * OUT_D +  0 + lo] = c0[q];
    ap[ri * OUT_D + 16 + lo] = c1[q];
    ap[ri * OUT_D + 32 + lo] = c2[q];
    ap[ri * OUT_D + 48 + lo] = c3[q];
  }
}

// ---------------- Kernel 4: combine partitions, normalize ----------------
__global__ __launch_bounds__(256) void k_combine(
    const float* __restrict__ accp, const float* __restrict__ lpart,
    float* __restrict__ out, int npart)
{
  int idx = blockIdx.x * 256 + threadIdx.x;   // 4096*64 total
  int i = idx >> 6;
  float s = 0.f, li = 0.f;
  for (int p = 0; p < npart; ++p) {
    s  += accp[(size_t)p * (NN * OUT_D) + idx];
    li += lpart[(size_t)p * NN + i];
  }
  out[idx] = s / li;
}

extern "C" void kernel_launch(void* const* d_in, const int* in_sizes, int n_in,
                              void* d_out, int out_size, void* d_ws, size_t ws_size,
                              hipStream_t stream)
{
  const float* X   = (const float*)d_in[0];
  const int*   adj = (const int*)d_in[1];
  const float* W   = (const float*)d_in[2];
  const float* a   = (const float*)d_in[3];
  float* out = (float*)d_out;

  char* ws = (char*)d_ws;
  float* s1  = (float*)ws;                    // 4096 f32
  float* s2  = (float*)(ws + 4096 * 4);       // 4096 f32
  float* s2m = (float*)(ws + 8192 * 4);       // 16 f32 (pad)
  short* hbT = (short*)(ws + 8208 * 4);       // 64*4096 bf16 = 512 KB
  char* base2 = ws + 8208 * 4 + (size_t)OUT_D * NN * 2;
  size_t fixed = (size_t)(base2 - ws);

  int npart = 1;
  for (int p = 8; p >= 1; p >>= 1) {
    size_t need = fixed + (size_t)p * (NN * OUT_D + NN) * 4;
    if (need <= ws_size) { npart = p; break; }
  }
  float* accp  = (float*)base2;
  float* lpart = (float*)(base2 + (size_t)npart * NN * OUT_D * 4);
  int jchunk = NN / npart;

  k_h<<<NN / 8, 256, 0, stream>>>(X, W, a, hbT, s1, s2);
  k_s2max<<<1, 256, 0, stream>>>(s2, s2m);
  dim3 grid_attn(NN / 64, npart);
  k_attn<<<grid_attn, 256, 0, stream>>>(adj, hbT, s1, s2, s2m, accp, lpart, jchunk);
  k_combine<<<(NN * OUT_D) / 256, 256, 0, stream>>>(accp, lpart, out, npart);
}

// Round 2
// 54.064 us; speedup vs baseline: 1.4373x; 1.4373x over previous
//
#include <hip/hip_runtime.h>
#include <hip/hip_bf16.h>

#define NN 4096
#define IN_DIM 512
#define OUT_D 64
#define LOG2E 1.44269504088896340736f

typedef __attribute__((ext_vector_type(8))) short short8v;
typedef __attribute__((ext_vector_type(4))) float f32x4;

__device__ __forceinline__ short to_bf16_rne(float x) {
  unsigned u = __builtin_bit_cast(unsigned, x);
  u = (u + 0x7FFFu + ((u >> 16) & 1u)) >> 16;
  return (short)u;
}
__device__ __forceinline__ float bf16_to_f(short h) {
  unsigned u = ((unsigned)(unsigned short)h) << 16;
  return __builtin_bit_cast(float, u);
}

// ---------------- Kernel 0a: X -> Xhi/Xlo bf16 split (row-major 4096x512) ----------
__global__ __launch_bounds__(256) void k_cvt(
    const float* __restrict__ X, short* __restrict__ Xhi, short* __restrict__ Xlo)
{
  int idx = blockIdx.x * 256 + threadIdx.x;   // handles 8 floats
  const float* p = X + (size_t)idx * 8;
  float4 v0 = *(const float4*)(p);
  float4 v1 = *(const float4*)(p + 4);
  float f[8]; *(float4*)f = v0; *(float4*)(f + 4) = v1;
  short8v hi, lo;
  #pragma unroll
  for (int r = 0; r < 8; ++r) {
    short h = to_bf16_rne(f[r]);
    hi[r] = h;
    lo[r] = to_bf16_rne(f[r] - bf16_to_f(h));
  }
  *(short8v*)(Xhi + (size_t)idx * 8) = hi;
  *(short8v*)(Xlo + (size_t)idx * 8) = lo;
}

// ---------------- Kernel 0b: pack W^T into A-fragment layout (hi/lo) ----------------
// Apack[m][t][l][r] = W[t*32 + 8*(l>>4) + r][m*16 + (l&15)], m=dtile(4), t=kstep(16)
__global__ __launch_bounds__(256) void k_wpack(
    const float* __restrict__ W, short* __restrict__ Ahi, short* __restrict__ Alo)
{
  int tid = blockIdx.x * 256 + threadIdx.x;   // 0..4095
  int l = tid & 63, t = (tid >> 6) & 15, m = tid >> 10;
  int dd = m * 16 + (l & 15);
  int kbase = t * 32 + 8 * (l >> 4);
  short8v hi, lo;
  #pragma unroll
  for (int r = 0; r < 8; ++r) {
    float w = W[(size_t)(kbase + r) * OUT_D + dd];
    short h = to_bf16_rne(w);
    hi[r] = h;
    lo[r] = to_bf16_rne(w - bf16_to_f(h));
  }
  *(short8v*)(Ahi + (size_t)tid * 8) = hi;
  *(short8v*)(Alo + (size_t)tid * 8) = lo;
}

// ---------------- Kernel 1: h^T = W^T @ X^T via MFMA (hi/lo split) ----------------
// grid = 256 blocks (16 rows each); 4 waves, wave m owns d-tile m (16 d's).
// Writes hbT bf16 [64][4096] + s1/s2 (f32, pre-scaled by log2e).
__global__ __launch_bounds__(256) void k_h_mfma(
    const short* __restrict__ Xhi, const short* __restrict__ Xlo,
    const short* __restrict__ Ahi, const short* __restrict__ Alo,
    const float* __restrict__ a,
    short* __restrict__ hbT, float* __restrict__ s1, float* __restrict__ s2)
{
  __shared__ float sm1[4][16], sm2[4][16];
  int m = threadIdx.x >> 6;
  int l = threadIdx.x & 63;
  int lo = l & 15, g = l >> 4;
  int row0 = blockIdx.x * 16;

  f32x4 acc = {0.f, 0.f, 0.f, 0.f};
  const short* xh = Xhi + (size_t)(row0 + lo) * IN_DIM + g * 8;
  const short* xl = Xlo + (size_t)(row0 + lo) * IN_DIM + g * 8;
  const short* ah = Ahi + ((size_t)(m * 16) * 64 + l) * 8;
  const short* al = Alo + ((size_t)(m * 16) * 64 + l) * 8;

  #pragma unroll
  for (int t = 0; t < 16; ++t) {
    short8v bhi = *(const short8v*)(xh + t * 32);
    short8v blo = *(const short8v*)(xl + t * 32);
    short8v fhi = *(const short8v*)(ah + (size_t)t * 64 * 8);
    short8v flo = *(const short8v*)(al + (size_t)t * 64 * 8);
    acc = __builtin_amdgcn_mfma_f32_16x16x32_bf16(fhi, bhi, acc, 0, 0, 0);
    acc = __builtin_amdgcn_mfma_f32_16x16x32_bf16(fhi, blo, acc, 0, 0, 0);
    acc = __builtin_amdgcn_mfma_f32_16x16x32_bf16(flo, bhi, acc, 0, 0, 0);
  }

  // C layout: col(=row of X) = l&15, row(=d within tile) = 4*g + q
  float p1 = 0.f, p2 = 0.f;
  #pragma unroll
  for (int q = 0; q < 4; ++q) {
    int d = m * 16 + 4 * g + q;
    hbT[(size_t)d * NN + row0 + lo] = to_bf16_rne(acc[q]);
    p1 = fmaf(acc[q], a[d], p1);
    p2 = fmaf(acc[q], a[OUT_D + d], p2);
  }
  p1 += __shfl_xor(p1, 16); p1 += __shfl_xor(p1, 32);
  p2 += __shfl_xor(p2, 16); p2 += __shfl_xor(p2, 32);
  if (l < 16) { sm1[m][l] = p1; sm2[m][l] = p2; }
  __syncthreads();
  if (threadIdx.x < 16) {
    int r = threadIdx.x;
    s1[row0 + r] = (sm1[0][r] + sm1[1][r] + sm1[2][r] + sm1[3][r]) * LOG2E;
    s2[row0 + r] = (sm2[0][r] + sm2[1][r] + sm2[2][r] + sm2[3][r]) * LOG2E;
  }
}

// ---------------- Fallback scalar k_h (only if ws too small) ----------------
__global__ __launch_bounds__(256) void k_h(
    const float* __restrict__ X, const float* __restrict__ W,
    const float* __restrict__ a,
    short* __restrict__ hbT, float* __restrict__ s1, float* __restrict__ s2)
{
  int tid = threadIdx.x;
  int dp = tid & 31;
  int rw = tid >> 5;
  int row = blockIdx.x * 8 + rw;
  const float* xrow = X + (size_t)row * IN_DIM;
  int d = dp * 2;
  float acc0 = 0.f, acc1 = 0.f;
  #pragma unroll 4
  for (int k4 = 0; k4 < IN_DIM / 4; ++k4) {
    float4 xv = *(const float4*)(xrow + k4 * 4);
    float2 w0 = *(const float2*)(W + (k4 * 4 + 0) * OUT_D + d);
    float2 w1 = *(const float2*)(W + (k4 * 4 + 1) * OUT_D + d);
    float2 w2 = *(const float2*)(W + (k4 * 4 + 2) * OUT_D + d);
    float2 w3 = *(const float2*)(W + (k4 * 4 + 3) * OUT_D + d);
    acc0 = fmaf(xv.x, w0.x, acc0); acc1 = fmaf(xv.x, w0.y, acc1);
    acc0 = fmaf(xv.y, w1.x, acc0); acc1 = fmaf(xv.y, w1.y, acc1);
    acc0 = fmaf(xv.z, w2.x, acc0); acc1 = fmaf(xv.z, w2.y, acc1);
    acc0 = fmaf(xv.w, w3.x, acc0); acc1 = fmaf(xv.w, w3.y, acc1);
  }
  hbT[(size_t)d * NN + row]       = to_bf16_rne(acc0);
  hbT[(size_t)(d + 1) * NN + row] = to_bf16_rne(acc1);
  float p1 = a[d] * acc0 + a[d + 1] * acc1;
  float p2 = a[OUT_D + d] * acc0 + a[OUT_D + d + 1] * acc1;
  #pragma unroll
  for (int off = 16; off >= 1; off >>= 1) {
    p1 += __shfl_xor(p1, off);
    p2 += __shfl_xor(p2, off);
  }
  if (dp == 0) { s1[row] = p1 * LOG2E; s2[row] = p2 * LOG2E; }
}

// ---------------- Kernel 2: global max of (scaled) s2 ----------------
__global__ __launch_bounds__(256) void k_s2max(const float* __restrict__ s2,
                                               float* __restrict__ s2max)
{
  __shared__ float red[256];
  float m = -3.0e38f;
  for (int i = threadIdx.x; i < NN; i += 256) m = fmaxf(m, s2[i]);
  red[threadIdx.x] = m;
  __syncthreads();
  for (int s = 128; s > 0; s >>= 1) {
    if ((int)threadIdx.x < s) red[threadIdx.x] = fmaxf(red[threadIdx.x], red[threadIdx.x + s]);
    __syncthreads();
  }
  if (threadIdx.x == 0) *s2max = red[0];
}

// ---------------- Kernel 3: fused masked-softmax-weight + P@H via MFMA ----------------
__global__ __launch_bounds__(256) void k_attn(
    const int* __restrict__ adj, const short* __restrict__ hbT,
    const float* __restrict__ s1, const float* __restrict__ s2,
    const float* __restrict__ s2maxp,
    float* __restrict__ accp, float* __restrict__ lpart, int jchunk)
{
  int w  = threadIdx.x >> 6;
  int l  = threadIdx.x & 63;
  int lo = l & 15, g = l >> 4;
  int part  = blockIdx.y;
  int ibase = blockIdx.x * 64 + w * 16;
  int row   = ibase + lo;

  float s1v = s1[row];
  float x = s1v + *s2maxp;
  float M = fmaxf(x, 0.01f * x);

  f32x4 c0 = {0.f,0.f,0.f,0.f}, c1 = {0.f,0.f,0.f,0.f};
  f32x4 c2 = {0.f,0.f,0.f,0.f}, c3 = {0.f,0.f,0.f,0.f};
  float lsum = 0.f;

  const int* adjrow = adj + (size_t)row * NN;
  int j0 = part * jchunk;
  int jj = j0 + g * 8;

  int4  pa0 = *(const int4*)(adjrow + jj);
  int4  pa1 = *(const int4*)(adjrow + jj + 4);
  float4 ps0 = *(const float4*)(s2 + jj);
  float4 ps1 = *(const float4*)(s2 + jj + 4);

  for (int js = 0; js < jchunk; js += 32) {
    int4 a0 = pa0, a1 = pa1;
    float4 t0 = ps0, t1 = ps1;
    int jn = jj + 32;
    if (js + 32 < jchunk) {
      pa0 = *(const int4*)(adjrow + jn);
      pa1 = *(const int4*)(adjrow + jn + 4);
      ps0 = *(const float4*)(s2 + jn);
      ps1 = *(const float4*)(s2 + jn + 4);
    }

    short8v b0 = *(const short8v*)(hbT + ((size_t)(lo)      << 12) + jj);
    short8v b1 = *(const short8v*)(hbT + ((size_t)(16 + lo) << 12) + jj);
    short8v b2 = *(const short8v*)(hbT + ((size_t)(32 + lo) << 12) + jj);
    short8v b3 = *(const short8v*)(hbT + ((size_t)(48 + lo) << 12) + jj);

    int av[8]; float sv[8];
    *(int4*)(av) = a0;  *(int4*)(av + 4) = a1;
    *(float4*)(sv) = t0; *(float4*)(sv + 4) = t1;

    short8v af;
    #pragma unroll
    for (int r = 0; r < 8; ++r) {
      float y = s1v + sv[r];
      float e = fmaxf(y, 0.01f * y);
      float p = exp2f(e - M);
      p = (av[r] > 0) ? p : 0.f;
      lsum += p;
      af[r] = to_bf16_rne(p);
    }

    c0 = __builtin_amdgcn_mfma_f32_16x16x32_bf16(af, b0, c0, 0, 0, 0);
    c1 = __builtin_amdgcn_mfma_f32_16x16x32_bf16(af, b1, c1, 0, 0, 0);
    c2 = __builtin_amdgcn_mfma_f32_16x16x32_bf16(af, b2, c2, 0, 0, 0);
    c3 = __builtin_amdgcn_mfma_f32_16x16x32_bf16(af, b3, c3, 0, 0, 0);
    jj = jn;
  }

  lsum += __shfl_xor(lsum, 16);
  lsum += __shfl_xor(lsum, 32);
  if (l < 16) lpart[(size_t)part * NN + ibase + l] = lsum;

  float* ap = accp + ((size_t)part * NN + ibase) * OUT_D;
  #pragma unroll
  for (int q = 0; q < 4; ++q) {
    int ri = g * 4 + q;
    ap[ri * OUT_D +  0 + lo] = c0[q];
    ap[ri * OUT_D + 16 + lo] = c1[q];
    ap[ri * OUT_D + 32 + lo] = c2[q];
    ap[ri * OUT_D + 48 + lo] = c3[q];
  }
}

// ---------------- Kernel 4: combine partitions, normalize ----------------
__global__ __launch_bounds__(256) void k_combine(
    const float* __restrict__ accp, const float* __restrict__ lpart,
    float* __restrict__ out, int npart)
{
  int idx = blockIdx.x * 256 + threadIdx.x;
  int i = idx >> 6;
  float s = 0.f, li = 0.f;
  for (int p = 0; p < npart; ++p) {
    s  += accp[(size_t)p * (NN * OUT_D) + idx];
    li += lpart[(size_t)p * NN + i];
  }
  out[idx] = s / li;
}

extern "C" void kernel_launch(void* const* d_in, const int* in_sizes, int n_in,
                              void* d_out, int out_size, void* d_ws, size_t ws_size,
                              hipStream_t stream)
{
  const float* X   = (const float*)d_in[0];
  const int*   adj = (const int*)d_in[1];
  const float* W   = (const float*)d_in[2];
  const float* a   = (const float*)d_in[3];
  float* out = (float*)d_out;

  char* ws = (char*)d_ws;
  size_t off = 0;
  float* s1  = (float*)(ws + off); off += NN * 4;
  float* s2  = (float*)(ws + off); off += NN * 4;
  float* s2m = (float*)(ws + off); off += 64;
  short* hbT = (short*)(ws + off); off += (size_t)OUT_D * NN * 2;   // 512 KB
  size_t fixed_old = off;

  short* Xhi = (short*)(ws + off); off += (size_t)NN * IN_DIM * 2;  // 4 MB
  short* Xlo = (short*)(ws + off); off += (size_t)NN * IN_DIM * 2;  // 4 MB
  short* Ahi = (short*)(ws + off); off += 4096 * 8 * 2;             // 64 KB
  short* Alo = (short*)(ws + off); off += 4096 * 8 * 2;             // 64 KB
  size_t fixed_new = off;

  // choose npart and path based on available workspace
  size_t per_part = (size_t)(NN * OUT_D + NN) * 4;
  int npart = 0; bool use_mfma = true;
  for (int p = 8; p >= 1; p >>= 1)
    if (fixed_new + (size_t)p * per_part <= ws_size) { npart = p; break; }
  if (npart == 0) {
    use_mfma = false;
    for (int p = 8; p >= 1; p >>= 1)
      if (fixed_old + (size_t)p * per_part <= ws_size) { npart = p; break; }
    if (npart == 0) npart = 1;
  }
  char* base2 = ws + (use_mfma ? fixed_new : fixed_old);
  float* accp  = (float*)base2;
  float* lpart = (float*)(base2 + (size_t)npart * NN * OUT_D * 4);
  int jchunk = NN / npart;

  if (use_mfma) {
    k_cvt<<<(NN * IN_DIM) / (8 * 256), 256, 0, stream>>>(X, Xhi, Xlo);
    k_wpack<<<16, 256, 0, stream>>>(W, Ahi, Alo);
    k_h_mfma<<<NN / 16, 256, 0, stream>>>(Xhi, Xlo, Ahi, Alo, a, hbT, s1, s2);
  } else {
    k_h<<<NN / 8, 256, 0, stream>>>(X, W, a, hbT, s1, s2);
  }
  k_s2max<<<1, 256, 0, stream>>>(s2, s2m);
  dim3 grid_attn(NN / 64, npart);
  k_attn<<<grid_attn, 256, 0, stream>>>(adj, hbT, s1, s2, s2m, accp, lpart, jchunk);
  k_combine<<<(NN * OUT_D) / 256, 256, 0, stream>>>(accp, lpart, out, npart);
}